// Round 3
// baseline (79.254 us; speedup 1.0000x reference)
//
#include <hip/hip_runtime.h>
#include <math.h>

// Problem constants (from reference)
#define B_    64
#define N_    2048
#define D_    512
#define C_    128
#define TOPK_ 8
#define LN_EPS_ 1e-5f

// ---------------------------------------------------------------------------
// Kernel 1: per-batch precompute (64 blocks).
//   cw[b][d] = ln_w[d] * W[d, y[b]]
//   cb[b]    = sum_d ln_b[d]*W[d,y[b]] + bias[y[b]]
//   su[b]    = sum_d cw[b][d]
//   len[b]   = popcount(mask row)  (mask is a prefix => len = valid length)
// Mask layout auto-detected via first word (lengths >= TOPK so mask[0..7]
// are all true): 1 -> int32, 0x01010101 -> bytes, else -> float.
// ---------------------------------------------------------------------------
__global__ __launch_bounds__(256) void prep_kernel(
    const float* __restrict__ ln_w, const float* __restrict__ ln_b,
    const float* __restrict__ W, const float* __restrict__ bias,
    const int* __restrict__ y, const unsigned char* __restrict__ mask,
    float* __restrict__ cw, float* __restrict__ cb, float* __restrict__ su,
    int* __restrict__ len) {
  int b = blockIdx.x;
  int t = threadIdx.x;
  int cls = y[b];
  __shared__ float red0[256];
  __shared__ float red1[256];
  __shared__ int   red2[256];
  float l0 = 0.f, l1 = 0.f;
  for (int d = t; d < D_; d += 256) {
    float wcol = W[d * C_ + cls];
    float u = ln_w[d] * wcol;
    cw[b * D_ + d] = u;
    l0 += ln_b[d] * wcol;
    l1 += u;
  }
  int cnt = 0;
  unsigned int tag = *(const unsigned int*)mask;
  if (tag == 1u) {
    const int* m32 = (const int*)mask;
    for (int i = t; i < N_; i += 256) cnt += (m32[b * N_ + i] != 0);
  } else if (tag == 0x01010101u) {
    for (int i = t; i < N_; i += 256) cnt += (mask[b * N_ + i] != 0);
  } else {
    const float* mf = (const float*)mask;
    for (int i = t; i < N_; i += 256) cnt += (mf[b * N_ + i] != 0.f);
  }
  red0[t] = l0; red1[t] = l1; red2[t] = cnt;
  __syncthreads();
  for (int s = 128; s > 0; s >>= 1) {
    if (t < s) {
      red0[t] += red0[t + s];
      red1[t] += red1[t + s];
      red2[t] += red2[t + s];
    }
    __syncthreads();
  }
  if (t == 0) {
    cb[b] = red0[0] + bias[cls];
    su[b] = red1[0];
    len[b] = red2[0];
  }
}

// ---------------------------------------------------------------------------
// Kernel 2 (HBM-bound): one wave per clip. Validity = n < len[b] (hot scalar
// line, no scattered mask load blocking the x loads). Valid clips: fused
// sum(x), sum(x^2), dot(x, cw) in one pass, shfl reduce.
// ---------------------------------------------------------------------------
__global__ __launch_bounds__(256) void score_kernel(
    const float* __restrict__ x, const float* __restrict__ cw,
    const float* __restrict__ cb, const float* __restrict__ su,
    const int* __restrict__ len, float* __restrict__ score) {
  int wave = threadIdx.x >> 6;
  int lane = threadIdx.x & 63;
  int clip = blockIdx.x * 4 + wave;          // 0 .. B*N-1
  int b = clip >> 11;                        // clip / N_
  int n = clip & (N_ - 1);

  if (n >= len[b]) {                         // wave-uniform, L2-broadcast-hot
    if (lane == 0) score[clip] = -INFINITY;
    return;
  }

  const float4* x4 = (const float4*)(x + (size_t)clip * D_);
  const float4* u4 = (const float4*)(cw + (size_t)b * D_);
  float4 xa = x4[lane];
  float4 xb = x4[lane + 64];
  float4 ua = u4[lane];
  float4 ub = u4[lane + 64];
  float s  = xa.x + xa.y + xa.z + xa.w + xb.x + xb.y + xb.z + xb.w;
  float sq = fmaf(xa.x, xa.x, fmaf(xa.y, xa.y, fmaf(xa.z, xa.z, xa.w * xa.w)))
           + fmaf(xb.x, xb.x, fmaf(xb.y, xb.y, fmaf(xb.z, xb.z, xb.w * xb.w)));
  float dt = fmaf(xa.x, ua.x, fmaf(xa.y, ua.y, fmaf(xa.z, ua.z, xa.w * ua.w)))
           + fmaf(xb.x, ub.x, fmaf(xb.y, ub.y, fmaf(xb.z, ub.z, xb.w * ub.w)));
  for (int off = 32; off > 0; off >>= 1) {
    s  += __shfl_xor(s, off);
    sq += __shfl_xor(sq, off);
    dt += __shfl_xor(dt, off);
  }
  if (lane == 0) {
    float mu = s * (1.f / D_);
    float var = sq * (1.f / D_) - mu * mu;
    float rstd = rsqrtf(var + LN_EPS_);
    score[clip] = rstd * (dt - mu * su[b]) + cb[b];
  }
}

// ---------------------------------------------------------------------------
// Kernel 3: fused topk + final logits + average. One block per batch.
// Phase 1: top-8 via block argmax (wave shfl reduce + 4-entry LDS combine),
//          ties -> smaller index (matches lax.top_k semantics for the set).
// Phase 2: 4 waves LayerNorm 2 selected clips each into LDS (float4 path).
// Phase 3: 1024 dots (8 clips x 128 classes) over 256 threads; W coalesced,
//          reused across 4 clips per load; xn_s reads are LDS broadcasts.
// Phase 4: average + bias -> out.
// ---------------------------------------------------------------------------
__global__ __launch_bounds__(256) void tail_kernel(
    const float* __restrict__ x, const float* __restrict__ ln_w,
    const float* __restrict__ ln_b, const float* __restrict__ W,
    const float* __restrict__ bias, const float* __restrict__ score,
    float* __restrict__ out) {
  int b = blockIdx.x;
  int t = threadIdx.x;
  int wave = t >> 6;
  int lane = t & 63;

  __shared__ float sv[4];
  __shared__ int   si[4];
  __shared__ int   top_s[TOPK_];
  __shared__ int   chosen_s;
  __shared__ float xn_s[TOPK_][D_];      // 16 KB
  __shared__ float partsum[2][C_];       // 1 KB

  // ---- Phase 1: top-8 ----
  float v[8];
  for (int j = 0; j < 8; ++j) v[j] = score[b * N_ + j * 256 + t];
  for (int k = 0; k < TOPK_; ++k) {
    float bv = -INFINITY;
    int bi = N_;
    for (int j = 0; j < 8; ++j) {
      int e = j * 256 + t;
      if (v[j] > bv || (v[j] == bv && e < bi)) { bv = v[j]; bi = e; }
    }
    for (int off = 32; off > 0; off >>= 1) {
      float ov = __shfl_xor(bv, off);
      int   oi = __shfl_xor(bi, off);
      if (ov > bv || (ov == bv && oi < bi)) { bv = ov; bi = oi; }
    }
    if (lane == 0) { sv[wave] = bv; si[wave] = bi; }
    __syncthreads();
    if (t == 0) {
      float cv = sv[0]; int ci = si[0];
      for (int w = 1; w < 4; ++w)
        if (sv[w] > cv || (sv[w] == cv && si[w] < ci)) { cv = sv[w]; ci = si[w]; }
      top_s[k] = ci;
      chosen_s = ci;
    }
    __syncthreads();
    int ch = chosen_s;
    if ((ch & 255) == t) v[ch >> 8] = -INFINITY;   // owner removes it
  }
  __syncthreads();

  // ---- Phase 2: LayerNorm the 8 selected clips into LDS ----
  const float4* lw4 = (const float4*)ln_w;
  const float4* lb4 = (const float4*)ln_b;
  for (int kk = wave; kk < TOPK_; kk += 4) {
    int n = top_s[kk];
    const float4* xp4 = (const float4*)(x + ((size_t)b * N_ + n) * D_);
    float4 xa = xp4[lane];
    float4 xb = xp4[lane + 64];
    float s  = xa.x + xa.y + xa.z + xa.w + xb.x + xb.y + xb.z + xb.w;
    float sq = fmaf(xa.x, xa.x, fmaf(xa.y, xa.y, fmaf(xa.z, xa.z, xa.w * xa.w)))
             + fmaf(xb.x, xb.x, fmaf(xb.y, xb.y, fmaf(xb.z, xb.z, xb.w * xb.w)));
    for (int off = 32; off > 0; off >>= 1) {
      s  += __shfl_xor(s, off);
      sq += __shfl_xor(sq, off);
    }
    float mu = s * (1.f / D_);
    float var = sq * (1.f / D_) - mu * mu;
    float rstd = rsqrtf(var + LN_EPS_);
    float4 wa = lw4[lane], wb = lw4[lane + 64];
    float4 ba = lb4[lane], bb = lb4[lane + 64];
    float4 ya, yb;
    ya.x = fmaf((xa.x - mu) * rstd, wa.x, ba.x);
    ya.y = fmaf((xa.y - mu) * rstd, wa.y, ba.y);
    ya.z = fmaf((xa.z - mu) * rstd, wa.z, ba.z);
    ya.w = fmaf((xa.w - mu) * rstd, wa.w, ba.w);
    yb.x = fmaf((xb.x - mu) * rstd, wb.x, bb.x);
    yb.y = fmaf((xb.y - mu) * rstd, wb.y, bb.y);
    yb.z = fmaf((xb.z - mu) * rstd, wb.z, bb.z);
    yb.w = fmaf((xb.w - mu) * rstd, wb.w, bb.w);
    ((float4*)xn_s[kk])[lane]      = ya;
    ((float4*)xn_s[kk])[lane + 64] = yb;
  }
  __syncthreads();

  // ---- Phase 3: dots. thread t -> class c = t&127, clips {g, g+2, g+4, g+6} ----
  int c = t & (C_ - 1);
  int g = t >> 7;
  float acc0 = 0.f, acc1 = 0.f, acc2 = 0.f, acc3 = 0.f;
  #pragma unroll 4
  for (int d = 0; d < D_; ++d) {
    float wv = W[d * C_ + c];                 // coalesced, reused x4
    acc0 = fmaf(xn_s[g][d],     wv, acc0);    // LDS broadcasts
    acc1 = fmaf(xn_s[g + 2][d], wv, acc1);
    acc2 = fmaf(xn_s[g + 4][d], wv, acc2);
    acc3 = fmaf(xn_s[g + 6][d], wv, acc3);
  }
  partsum[g][c] = acc0 + acc1 + acc2 + acc3;
  __syncthreads();

  // ---- Phase 4: average + bias ----
  if (t < C_)
    out[(size_t)b * C_ + t] =
        (partsum[0][t] + partsum[1][t]) * (1.f / TOPK_) + bias[t];
}

// ---------------------------------------------------------------------------
extern "C" void kernel_launch(void* const* d_in, const int* in_sizes, int n_in,
                              void* d_out, int out_size, void* d_ws, size_t ws_size,
                              hipStream_t stream) {
  const float* x    = (const float*)d_in[0];
  const float* ln_w = (const float*)d_in[1];
  const float* ln_b = (const float*)d_in[2];
  const float* W    = (const float*)d_in[3];
  const float* bias = (const float*)d_in[4];
  const unsigned char* mask = (const unsigned char*)d_in[5];
  const int* y      = (const int*)d_in[6];
  float* out = (float*)d_out;

  char* ws = (char*)d_ws;
  float* cw    = (float*)ws;  ws += (size_t)B_ * D_ * sizeof(float);     // 128 KB
  float* cb    = (float*)ws;  ws += (size_t)B_ * sizeof(float);
  float* su    = (float*)ws;  ws += (size_t)B_ * sizeof(float);
  int*   len   = (int*)ws;    ws += (size_t)B_ * sizeof(int);
  float* score = (float*)ws;                                             // 512 KB

  prep_kernel <<<B_, 256, 0, stream>>>(ln_w, ln_b, W, bias, y, mask, cw, cb, su, len);
  score_kernel<<<(B_ * N_) / 4, 256, 0, stream>>>(x, cw, cb, su, len, score);
  tail_kernel <<<B_, 256, 0, stream>>>(x, ln_w, ln_b, W, bias, score, out);
}

// Round 4
// 64.724 us; speedup vs baseline: 1.2245x; 1.2245x over previous
//
#include <hip/hip_runtime.h>
#include <math.h>

// Problem constants (from reference)
#define B_    64
#define N_    2048
#define D_    512
#define C_    128
#define TOPK_ 8
#define LN_EPS_ 1e-5f

// ---------------------------------------------------------------------------
// Kernel 1: per-batch precompute (64 blocks).
//   cw[b][d] = ln_w[d] * W[d, y[b]]
//   cb[b]    = sum_d ln_b[d]*W[d,y[b]] + bias[y[b]]
//   su[b]    = sum_d cw[b][d]
//   len[b]   = popcount(mask row)  (mask is a prefix => len = valid length)
// Mask layout auto-detected via first word (lengths >= TOPK so mask[0..7]
// are all true): 1 -> int32, 0x01010101 -> bytes, else -> float.
// ---------------------------------------------------------------------------
__global__ __launch_bounds__(256) void prep_kernel(
    const float* __restrict__ ln_w, const float* __restrict__ ln_b,
    const float* __restrict__ W, const float* __restrict__ bias,
    const int* __restrict__ y, const unsigned char* __restrict__ mask,
    float* __restrict__ cw, float* __restrict__ cb, float* __restrict__ su,
    int* __restrict__ len) {
  int b = blockIdx.x;
  int t = threadIdx.x;
  int cls = y[b];
  __shared__ float red0[256];
  __shared__ float red1[256];
  __shared__ int   red2[256];
  float l0 = 0.f, l1 = 0.f;
  for (int d = t; d < D_; d += 256) {
    float wcol = W[d * C_ + cls];
    float u = ln_w[d] * wcol;
    cw[b * D_ + d] = u;
    l0 += ln_b[d] * wcol;
    l1 += u;
  }
  int cnt = 0;
  unsigned int tag = *(const unsigned int*)mask;
  if (tag == 1u) {
    const int* m32 = (const int*)mask;
    for (int i = t; i < N_; i += 256) cnt += (m32[b * N_ + i] != 0);
  } else if (tag == 0x01010101u) {
    for (int i = t; i < N_; i += 256) cnt += (mask[b * N_ + i] != 0);
  } else {
    const float* mf = (const float*)mask;
    for (int i = t; i < N_; i += 256) cnt += (mf[b * N_ + i] != 0.f);
  }
  red0[t] = l0; red1[t] = l1; red2[t] = cnt;
  __syncthreads();
  for (int s = 128; s > 0; s >>= 1) {
    if (t < s) {
      red0[t] += red0[t + s];
      red1[t] += red1[t + s];
      red2[t] += red2[t + s];
    }
    __syncthreads();
  }
  if (t == 0) {
    cb[b] = red0[0] + bias[cls];
    su[b] = red1[0];
    len[b] = red2[0];
  }
}

// ---------------------------------------------------------------------------
// Kernel 2 (HBM-bound): FOUR clips per wave (same batch). 8 x-row float4
// loads issued up-front (8 KB MLP per wave, 4x the old version); cw loaded
// once per wave and reused across the 4 clips (cw L2 traffic /4); 12
// independent shfl-reduce chains interleaved for pipelining. Groups of 4
// never straddle a batch (N % 4 == 0). Partial-validity groups handled at
// the write (x loads past len are harmless reads).
// ---------------------------------------------------------------------------
__global__ __launch_bounds__(256) void score_kernel(
    const float* __restrict__ x, const float* __restrict__ cw,
    const float* __restrict__ cb, const float* __restrict__ su,
    const int* __restrict__ len, float* __restrict__ score) {
  int wave = threadIdx.x >> 6;
  int lane = threadIdx.x & 63;
  int grp  = blockIdx.x * 4 + wave;          // group of 4 consecutive clips
  int clip0 = grp * 4;
  int b  = clip0 >> 11;                      // clip0 / N_
  int n0 = clip0 & (N_ - 1);
  int L  = len[b];

  if (n0 >= L) {                             // whole group invalid
    if (lane < 4) score[clip0 + lane] = -INFINITY;
    return;
  }

  const float4* x4 = (const float4*)(x + (size_t)clip0 * D_);
  const float4* u4 = (const float4*)(cw + (size_t)b * D_);
  float4 ua = u4[lane];
  float4 ub = u4[lane + 64];

  float4 xa[4], xb[4];
  #pragma unroll
  for (int c = 0; c < 4; ++c) {              // 8 loads, all independent
    xa[c] = x4[lane + c * 128];
    xb[c] = x4[lane + 64 + c * 128];
  }

  float s[4], sq[4], dt[4];
  #pragma unroll
  for (int c = 0; c < 4; ++c) {
    s[c]  = xa[c].x + xa[c].y + xa[c].z + xa[c].w
          + xb[c].x + xb[c].y + xb[c].z + xb[c].w;
    sq[c] = fmaf(xa[c].x, xa[c].x, fmaf(xa[c].y, xa[c].y,
            fmaf(xa[c].z, xa[c].z, xa[c].w * xa[c].w)))
          + fmaf(xb[c].x, xb[c].x, fmaf(xb[c].y, xb[c].y,
            fmaf(xb[c].z, xb[c].z, xb[c].w * xb[c].w)));
    dt[c] = fmaf(xa[c].x, ua.x, fmaf(xa[c].y, ua.y,
            fmaf(xa[c].z, ua.z, xa[c].w * ua.w)))
          + fmaf(xb[c].x, ub.x, fmaf(xb[c].y, ub.y,
            fmaf(xb[c].z, ub.z, xb[c].w * ub.w)));
  }

  // 12 independent butterfly chains, interleaved per round
  #pragma unroll
  for (int off = 32; off > 0; off >>= 1) {
    #pragma unroll
    for (int c = 0; c < 4; ++c) {
      s[c]  += __shfl_xor(s[c],  off);
      sq[c] += __shfl_xor(sq[c], off);
      dt[c] += __shfl_xor(dt[c], off);
    }
  }

  float cbv = cb[b], suv = su[b];
  float val[4];
  #pragma unroll
  for (int c = 0; c < 4; ++c) {
    float mu = s[c] * (1.f / D_);
    float var = sq[c] * (1.f / D_) - mu * mu;
    float rstd = rsqrtf(var + LN_EPS_);
    val[c] = rstd * (dt[c] - mu * suv) + cbv;
  }
  if (lane < 4) {
    float v = (lane == 0) ? val[0] : (lane == 1) ? val[1]
            : (lane == 2) ? val[2] : val[3];
    score[clip0 + lane] = (n0 + lane < L) ? v : -INFINITY;
  }
}

// ---------------------------------------------------------------------------
// Kernel 3: per-batch top-8, ONE WAVE per batch, shfl-only (no barriers).
// Ties -> smaller index (matches lax.top_k). 4 batches per 256-thread block.
// ---------------------------------------------------------------------------
__global__ __launch_bounds__(256) void topk_kernel(
    const float* __restrict__ score, int* __restrict__ topidx) {
  int wave = threadIdx.x >> 6;
  int lane = threadIdx.x & 63;
  int b = blockIdx.x * 4 + wave;
  float v[32];                                // N_/64 = 32 scores per lane
  for (int j = 0; j < 32; ++j) v[j] = score[b * N_ + j * 64 + lane];
  for (int k = 0; k < TOPK_; ++k) {
    float bv = -INFINITY;
    int bi = N_;
    for (int j = 0; j < 32; ++j) {
      int e = j * 64 + lane;
      if (v[j] > bv || (v[j] == bv && e < bi)) { bv = v[j]; bi = e; }
    }
    for (int off = 32; off > 0; off >>= 1) {
      float ov = __shfl_xor(bv, off);
      int   oi = __shfl_xor(bi, off);
      if (ov > bv || (ov == bv && oi < bi)) { bv = ov; bi = oi; }
    }
    // bv/bi now uniform across the wave
    if (lane == 0) topidx[b * TOPK_ + k] = bi;
    if ((bi & 63) == lane) v[bi >> 6] = -INFINITY;   // owner removes it
  }
}

// ---------------------------------------------------------------------------
// Kernel 4: one block per selected clip (B*TOPK = 512 blocks). LN + full
// 128-class logits -> sel[b][k][C].
// ---------------------------------------------------------------------------
__global__ __launch_bounds__(256) void final_kernel(
    const float* __restrict__ x, const float* __restrict__ ln_w,
    const float* __restrict__ ln_b, const float* __restrict__ W,
    const float* __restrict__ bias, const int* __restrict__ topidx,
    float* __restrict__ sel) {
  int b = blockIdx.x >> 3;
  int k = blockIdx.x & 7;
  int t = threadIdx.x;
  int n = topidx[b * TOPK_ + k];
  __shared__ float xs[D_];
  __shared__ float red[256];
  __shared__ float stats[2];
  const float4* xp4 = (const float4*)(x + ((size_t)b * N_ + n) * D_);
  float lsum = 0.f, lsq = 0.f;
  if (t < 128) {                               // 128 float4 = 512 floats
    float4 xv = xp4[t];
    ((float4*)xs)[t] = xv;
    lsum = xv.x + xv.y + xv.z + xv.w;
    lsq = fmaf(xv.x, xv.x, fmaf(xv.y, xv.y, fmaf(xv.z, xv.z, xv.w * xv.w)));
  }
  red[t] = lsum;
  __syncthreads();
  for (int s = 128; s > 0; s >>= 1) { if (t < s) red[t] += red[t + s]; __syncthreads(); }
  if (t == 0) stats[0] = red[0] * (1.f / D_);
  __syncthreads();
  red[t] = lsq;
  __syncthreads();
  for (int s = 128; s > 0; s >>= 1) { if (t < s) red[t] += red[t + s]; __syncthreads(); }
  if (t == 0) {
    float mu = stats[0];
    float var = red[0] * (1.f / D_) - mu * mu;
    stats[1] = rsqrtf(var + LN_EPS_);
  }
  __syncthreads();
  float mu = stats[0], rstd = stats[1];
  for (int d = t; d < D_; d += 256)
    xs[d] = fmaf((xs[d] - mu) * rstd, ln_w[d], ln_b[d]);
  __syncthreads();
  if (t < C_) {
    float dot = 0.f;
    for (int d = 0; d < D_; ++d)
      dot = fmaf(xs[d], W[d * C_ + t], dot);   // xs broadcast; W coalesced
    sel[((size_t)b * TOPK_ + k) * C_ + t] = dot + bias[t];
  }
}

// ---------------------------------------------------------------------------
// Kernel 5: average the 8 selected-clip logit rows per batch.
// ---------------------------------------------------------------------------
__global__ __launch_bounds__(128) void avg_kernel(
    const float* __restrict__ sel, float* __restrict__ out) {
  int b = blockIdx.x;
  int t = threadIdx.x;
  float acc = 0.f;
  for (int k = 0; k < TOPK_; ++k)
    acc += sel[((size_t)b * TOPK_ + k) * C_ + t];
  out[(size_t)b * C_ + t] = acc * (1.f / TOPK_);
}

// ---------------------------------------------------------------------------
extern "C" void kernel_launch(void* const* d_in, const int* in_sizes, int n_in,
                              void* d_out, int out_size, void* d_ws, size_t ws_size,
                              hipStream_t stream) {
  const float* x    = (const float*)d_in[0];
  const float* ln_w = (const float*)d_in[1];
  const float* ln_b = (const float*)d_in[2];
  const float* W    = (const float*)d_in[3];
  const float* bias = (const float*)d_in[4];
  const unsigned char* mask = (const unsigned char*)d_in[5];
  const int* y      = (const int*)d_in[6];
  float* out = (float*)d_out;

  char* ws = (char*)d_ws;
  float* cw    = (float*)ws;  ws += (size_t)B_ * D_ * sizeof(float);     // 128 KB
  float* cb    = (float*)ws;  ws += (size_t)B_ * sizeof(float);
  float* su    = (float*)ws;  ws += (size_t)B_ * sizeof(float);
  int*   len   = (int*)ws;    ws += (size_t)B_ * sizeof(int);
  float* score = (float*)ws;  ws += (size_t)B_ * N_ * sizeof(float);     // 512 KB
  int*   tidx  = (int*)ws;    ws += (size_t)B_ * TOPK_ * sizeof(int);    // 2 KB
  float* sel   = (float*)ws;                                             // 256 KB

  prep_kernel <<<B_, 256, 0, stream>>>(ln_w, ln_b, W, bias, y, mask, cw, cb, su, len);
  score_kernel<<<(B_ * N_) / 16, 256, 0, stream>>>(x, cw, cb, su, len, score);
  topk_kernel <<<B_ / 4, 256, 0, stream>>>(score, tidx);
  final_kernel<<<B_ * TOPK_, 256, 0, stream>>>(x, ln_w, ln_b, W, bias, tidx, sel);
  avg_kernel  <<<B_, 128, 0, stream>>>(sel, out);
}

// Round 5
// 63.700 us; speedup vs baseline: 1.2442x; 1.0161x over previous
//
#include <hip/hip_runtime.h>
#include <math.h>

// Problem constants (from reference)
#define B_    64
#define N_    2048
#define D_    512
#define C_    128
#define TOPK_ 8
#define LN_EPS_ 1e-5f

// ---------------------------------------------------------------------------
// Kernel 1: per-batch precompute (64 blocks).
//   cw[b][d] = ln_w[d] * W[d, y[b]]
//   cb[b]    = sum_d ln_b[d]*W[d,y[b]] + bias[y[b]]
//   su[b]    = sum_d cw[b][d]
//   len[b]   = popcount(mask row)  (mask is a prefix => len = valid length)
// Mask layout auto-detected via first word (lengths >= TOPK so mask[0..7]
// are all true): 1 -> int32, 0x01010101 -> bytes, else -> float.
// ---------------------------------------------------------------------------
__global__ __launch_bounds__(256) void prep_kernel(
    const float* __restrict__ ln_w, const float* __restrict__ ln_b,
    const float* __restrict__ W, const float* __restrict__ bias,
    const int* __restrict__ y, const unsigned char* __restrict__ mask,
    float* __restrict__ cw, float* __restrict__ cb, float* __restrict__ su,
    int* __restrict__ len) {
  int b = blockIdx.x;
  int t = threadIdx.x;
  int cls = y[b];
  __shared__ float red0[256];
  __shared__ float red1[256];
  __shared__ int   red2[256];
  float l0 = 0.f, l1 = 0.f;
  for (int d = t; d < D_; d += 256) {
    float wcol = W[d * C_ + cls];
    float u = ln_w[d] * wcol;
    cw[b * D_ + d] = u;
    l0 += ln_b[d] * wcol;
    l1 += u;
  }
  int cnt = 0;
  unsigned int tag = *(const unsigned int*)mask;
  if (tag == 1u) {
    const int* m32 = (const int*)mask;
    for (int i = t; i < N_; i += 256) cnt += (m32[b * N_ + i] != 0);
  } else if (tag == 0x01010101u) {
    for (int i = t; i < N_; i += 256) cnt += (mask[b * N_ + i] != 0);
  } else {
    const float* mf = (const float*)mask;
    for (int i = t; i < N_; i += 256) cnt += (mf[b * N_ + i] != 0.f);
  }
  red0[t] = l0; red1[t] = l1; red2[t] = cnt;
  __syncthreads();
  for (int s = 128; s > 0; s >>= 1) {
    if (t < s) {
      red0[t] += red0[t + s];
      red1[t] += red1[t + s];
      red2[t] += red2[t + s];
    }
    __syncthreads();
  }
  if (t == 0) {
    cb[b] = red0[0] + bias[cls];
    su[b] = red1[0];
    len[b] = red2[0];
  }
}

// ---------------------------------------------------------------------------
// Kernel 2 (HBM-bound): ONE CLIP PER 16-LANE GROUP (4 clips/wave, 16/block).
// Reduce needs only xor offsets 1,2,4,8 -> 12 shfl per wave (was 72).
// cw staged once per block in LDS (2 KB) -> no redundant L2 re-reads.
// Block-level early-exit for fully-invalid blocks (before any barrier);
// wave-level exit after the barrier; per-clip validity at the write.
// x loads: per instruction 4 x 256B contiguous segments -> fully coalesced.
// ---------------------------------------------------------------------------
__global__ __launch_bounds__(256) void score_kernel(
    const float* __restrict__ x, const float* __restrict__ cw,
    const float* __restrict__ cb, const float* __restrict__ su,
    const int* __restrict__ len, float* __restrict__ score) {
  int t = threadIdx.x;
  int wave = t >> 6;
  int lane = t & 63;
  int lg   = lane & 15;                    // lane within 16-group
  int g    = lane >> 4;                    // group 0..3 = clip within wave
  int blk_clip0 = blockIdx.x * 16;
  int b    = blk_clip0 >> 11;              // clip / N_
  int nblk = blk_clip0 & (N_ - 1);
  int L = len[b];

  __shared__ float4 cw_s[D_ / 4];          // 2 KB

  if (nblk >= L) {                         // block-uniform: all 16 invalid
    if (t < 16) score[blk_clip0 + t] = -INFINITY;
    return;
  }
  if (t < 128) cw_s[t] = ((const float4*)(cw + (size_t)b * D_))[t];
  __syncthreads();

  int clip0 = blk_clip0 + wave * 4;        // wave's first clip
  int n0 = clip0 & (N_ - 1);
  if (n0 >= L) {                           // wave-uniform (after barrier: safe)
    if (lane < 4) score[clip0 + lane] = -INFINITY;
    return;
  }

  int cg = clip0 + g;                      // this group's clip
  const float4* xg = (const float4*)(x + (size_t)cg * D_);
  float4 xv[8];
  #pragma unroll
  for (int j = 0; j < 8; ++j) xv[j] = xg[j * 16 + lg];   // 8 indep loads

  float s = 0.f, sq = 0.f, dt = 0.f;
  #pragma unroll
  for (int j = 0; j < 8; ++j) {
    float4 u = cw_s[j * 16 + lg];
    float4 a = xv[j];
    s  += a.x + a.y + a.z + a.w;
    sq  = fmaf(a.x, a.x, fmaf(a.y, a.y, fmaf(a.z, a.z, fmaf(a.w, a.w, sq))));
    dt  = fmaf(a.x, u.x, fmaf(a.y, u.y, fmaf(a.z, u.z, fmaf(a.w, u.w, dt))));
  }
  #pragma unroll
  for (int off = 1; off < 16; off <<= 1) { // 4 rounds x 3 = 12 shfl
    s  += __shfl_xor(s,  off);
    sq += __shfl_xor(sq, off);
    dt += __shfl_xor(dt, off);
  }
  if (lg == 0) {
    float mu = s * (1.f / D_);
    float var = sq * (1.f / D_) - mu * mu;
    float rstd = rsqrtf(var + LN_EPS_);
    float val = rstd * (dt - mu * su[b]) + cb[b];
    score[cg] = (n0 + g < L) ? val : -INFINITY;
  }
}

// ---------------------------------------------------------------------------
// Kernel 3: fused tail. 512 blocks x 128 threads; block (b,k).
// Wave 0 redundantly computes batch b's top-8 (identical across the 8 blocks
// of b -> deterministic). Then LN of winner k via wave-shfl, normalize into
// LDS, class-dot with uniform float4 LDS broadcasts (128 ds ops/wave), and
// atomicAdd average into out (out zeroed by in-graph memset).
// ---------------------------------------------------------------------------
__global__ __launch_bounds__(128) void tail_kernel(
    const float* __restrict__ x, const float* __restrict__ ln_w,
    const float* __restrict__ ln_b, const float* __restrict__ W,
    const float* __restrict__ bias, const float* __restrict__ score,
    float* __restrict__ out) {
  int b = blockIdx.x >> 3;
  int k = blockIdx.x & 7;
  int t = threadIdx.x;
  int lane = t & 63;

  __shared__ int   top_s[TOPK_];
  __shared__ float xn_s[D_];               // 2 KB
  __shared__ float red_s[2][2];

  // ---- top-8 of batch b (wave 0 only; ties -> smaller index) ----
  if (t < 64) {
    float v[32];
    #pragma unroll
    for (int j = 0; j < 32; ++j) v[j] = score[b * N_ + j * 64 + lane];
    for (int k2 = 0; k2 < TOPK_; ++k2) {
      float bv = -INFINITY;
      int bi = N_;
      #pragma unroll
      for (int j = 0; j < 32; ++j) {
        int e = j * 64 + lane;
        if (v[j] > bv || (v[j] == bv && e < bi)) { bv = v[j]; bi = e; }
      }
      for (int off = 32; off > 0; off >>= 1) {
        float ov = __shfl_xor(bv, off);
        int   oi = __shfl_xor(bi, off);
        if (ov > bv || (ov == bv && oi < bi)) { bv = ov; bi = oi; }
      }
      if (lane == 0) top_s[k2] = bi;
      if ((bi & 63) == lane) v[bi >> 6] = -INFINITY;   // owner removes it
    }
  }
  __syncthreads();

  // ---- LayerNorm winner k (128 threads, float4) ----
  int n = top_s[k];
  const float4* xp4 = (const float4*)(x + ((size_t)b * N_ + n) * D_);
  float4 xv = xp4[t];
  float s  = xv.x + xv.y + xv.z + xv.w;
  float sq = fmaf(xv.x, xv.x, fmaf(xv.y, xv.y, fmaf(xv.z, xv.z, xv.w * xv.w)));
  for (int off = 32; off > 0; off >>= 1) {
    s  += __shfl_xor(s,  off);
    sq += __shfl_xor(sq, off);
  }
  if (lane == 0) { red_s[t >> 6][0] = s; red_s[t >> 6][1] = sq; }
  __syncthreads();
  float mu   = (red_s[0][0] + red_s[1][0]) * (1.f / D_);
  float var  = (red_s[0][1] + red_s[1][1]) * (1.f / D_) - mu * mu;
  float rstd = rsqrtf(var + LN_EPS_);
  float4 wv = ((const float4*)ln_w)[t];
  float4 bv = ((const float4*)ln_b)[t];
  float4 yv;
  yv.x = fmaf((xv.x - mu) * rstd, wv.x, bv.x);
  yv.y = fmaf((xv.y - mu) * rstd, wv.y, bv.y);
  yv.z = fmaf((xv.z - mu) * rstd, wv.z, bv.z);
  yv.w = fmaf((xv.w - mu) * rstd, wv.w, bv.w);
  ((float4*)xn_s)[t] = yv;
  __syncthreads();

  // ---- dot: thread t = class t; xn via uniform float4 broadcast ----
  float a0 = 0.f, a1 = 0.f, a2 = 0.f, a3 = 0.f;
  #pragma unroll 4
  for (int ch = 0; ch < D_ / 4; ++ch) {
    float4 xn = ((const float4*)xn_s)[ch];           // LDS broadcast
    a0 = fmaf(xn.x, W[(ch * 4 + 0) * C_ + t], a0);   // W coalesced (256B/instr)
    a1 = fmaf(xn.y, W[(ch * 4 + 1) * C_ + t], a1);
    a2 = fmaf(xn.z, W[(ch * 4 + 2) * C_ + t], a2);
    a3 = fmaf(xn.w, W[(ch * 4 + 3) * C_ + t], a3);
  }
  float dot = (a0 + a1) + (a2 + a3);
  atomicAdd(&out[b * C_ + t], (dot + bias[t]) * (1.f / TOPK_));
}

// ---------------------------------------------------------------------------
extern "C" void kernel_launch(void* const* d_in, const int* in_sizes, int n_in,
                              void* d_out, int out_size, void* d_ws, size_t ws_size,
                              hipStream_t stream) {
  const float* x    = (const float*)d_in[0];
  const float* ln_w = (const float*)d_in[1];
  const float* ln_b = (const float*)d_in[2];
  const float* W    = (const float*)d_in[3];
  const float* bias = (const float*)d_in[4];
  const unsigned char* mask = (const unsigned char*)d_in[5];
  const int* y      = (const int*)d_in[6];
  float* out = (float*)d_out;

  char* ws = (char*)d_ws;
  float* cw    = (float*)ws;  ws += (size_t)B_ * D_ * sizeof(float);     // 128 KB
  float* cb    = (float*)ws;  ws += (size_t)B_ * sizeof(float);
  float* su    = (float*)ws;  ws += (size_t)B_ * sizeof(float);
  int*   len   = (int*)ws;    ws += (size_t)B_ * sizeof(int);
  float* score = (float*)ws;                                             // 512 KB

  // out accumulated via atomics -> zero it every call (graph-capturable).
  hipMemsetAsync(out, 0, (size_t)B_ * C_ * sizeof(float), stream);

  prep_kernel <<<B_, 256, 0, stream>>>(ln_w, ln_b, W, bias, y, mask, cw, cb, su, len);
  score_kernel<<<(B_ * N_) / 16, 256, 0, stream>>>(x, cw, cb, su, len, score);
  tail_kernel <<<B_ * TOPK_, 128, 0, stream>>>(x, ln_w, ln_b, W, bias, score, out);
}